// Round 10
// baseline (475.275 us; speedup 1.0000x reference)
//
#include <hip/hip_runtime.h>
#include <math.h>

#define N_NODES 50000
#define N_EDGES 800000
#define E2 (N_EDGES + N_NODES)   // with self loops
#define F_IN 512
#define HEADS 8
#define HID 32
#define HC 256                    // HEADS*HID
#define NCLASS 32
#define NEG_SLOPE 0.2f

typedef unsigned int uint;
typedef unsigned short ushort;
typedef __attribute__((ext_vector_type(8))) short bf16x8;   // 8 bf16 (4 VGPRs)
typedef __attribute__((ext_vector_type(4))) float f32x4;

#define GLOBAL_LOAD_LDS16(g, l) \
    __builtin_amdgcn_global_load_lds((const __attribute__((address_space(1))) void*)(g), \
                                     (__attribute__((address_space(3))) void*)(l), 16, 0, 0)

__device__ inline uint bf16_rne_bits(float f) {
    uint u = __float_as_uint(f);
    return (u + 0x7fffu + ((u >> 16) & 1u)) >> 16;
}
__device__ inline float bf2f(ushort u) { return __uint_as_float(((uint)u) << 16); }

// ------------------------------------------------ W1 [512][256] -> W1^T hi/lo bf16 [256][512]
__global__ void split_w1t_kernel(const float* __restrict__ W1,
                                 ushort* __restrict__ hi, ushort* __restrict__ lo) {
    int t = blockIdx.x * 256 + threadIdx.x;      // t = n*512 + k, t < 131072
    int n = t >> 9, k = t & 511;
    float f = W1[k * 256 + n];
    uint h = bf16_rne_bits(f);
    float r = f - __uint_as_float(h << 16);
    hi[t] = (ushort)h;
    lo[t] = (ushort)bf16_rne_bits(r);
}

// ------------------------------------------------ W2 [256][32] -> W2^T hi/lo bf16 [32][256]
__global__ void split_w2t_kernel(const float* __restrict__ W2,
                                 ushort* __restrict__ hi, ushort* __restrict__ lo) {
    int t = blockIdx.x * 256 + threadIdx.x;      // t = n*256 + k, t < 8192
    int n = t >> 8, k = t & 255;
    float f = W2[k * 32 + n];
    uint h = bf16_rne_bits(f);
    float r = f - __uint_as_float(h << 16);
    hi[t] = (ushort)h;
    lo[t] = (ushort)bf16_rne_bits(r);
}

// ------------------------------------------------ MFMA GEMM1: h1b[M,256] = x @ W1 (split bf16, 3-term)
// NO LDS, NO BARRIERS: A and B fragments loaded directly from global. A-fragment
// layout (lane fm=row, quad=k-chunk) makes each lane's load 32B contiguous and each
// wave instruction cover whole 128B lines. Waves fully independent -> latency hidden
// by 12 waves/CU + compiler load hoisting (no vmcnt(0) drain anywhere in the loop).
// + fused scores1 from fp32 acc.
__global__ void __launch_bounds__(256) gemm1_mfma_kernel(const uint* __restrict__ xp,
        const ushort* __restrict__ bhi, const ushort* __restrict__ blo,
        const float* __restrict__ as1, const float* __restrict__ ad1,
        ushort* __restrict__ C, float* __restrict__ ssrc, float* __restrict__ sdst, int M) {
    const int tid = threadIdx.x, lane = tid & 63, wave = tid >> 6;
    const int bm = blockIdx.x * 128, bn = blockIdx.y * 128;
    const int fm = lane & 15, quad = lane >> 4;
    const int wm = (wave >> 1) * 64, wn = (wave & 1) * 64;

    // A row pointers (i = 0..3), clamped; each lane reads 32B contiguous per (i,kk)
    const uint* arp[4];
    #pragma unroll
    for (int i = 0; i < 4; ++i) {
        int row = bm + wm + i * 16 + fm;
        if (row > M - 1) row = M - 1;
        arp[i] = xp + (size_t)row * 512 + quad * 8;
    }
    // B row pointers (this wave's two heads' rows; w1t is L2-resident)
    const ushort* bhp = bhi + (size_t)(bn + wn + fm) * 512 + quad * 8;
    const ushort* blp = blo + (size_t)(bn + wn + fm) * 512 + quad * 8;

    f32x4 acc[4][4] = {};

    #pragma unroll 4
    for (int kk = 0; kk < 16; ++kk) {
        // B fragments (16B/lane each)
        bf16x8 bh[4], bl[4];
        #pragma unroll
        for (int j = 0; j < 4; ++j) {
            size_t off = (size_t)j * 16 * 512 + kk * 32;
            bh[j] = *(const bf16x8*)(bhp + off);
            bl[j] = *(const bf16x8*)(blp + off);
        }
        // A fragments: 32B/lane, split hi/lo on the fly
        bf16x8 ah[4], al[4];
        #pragma unroll
        for (int i = 0; i < 4; ++i) {
            uint4 c0 = *(const uint4*)(arp[i] + kk * 32);
            uint4 c1 = *(const uint4*)(arp[i] + kk * 32 + 4);
            union { uint u[4]; bf16x8 v; } H, L;
            H.u[0] = __builtin_amdgcn_perm(c0.y, c0.x, 0x07060302u);
            H.u[1] = __builtin_amdgcn_perm(c0.w, c0.z, 0x07060302u);
            H.u[2] = __builtin_amdgcn_perm(c1.y, c1.x, 0x07060302u);
            H.u[3] = __builtin_amdgcn_perm(c1.w, c1.z, 0x07060302u);
            uint r0 = __float_as_uint(__uint_as_float(c0.x) - __uint_as_float(c0.x & 0xffff0000u));
            uint r1 = __float_as_uint(__uint_as_float(c0.y) - __uint_as_float(c0.y & 0xffff0000u));
            uint r2 = __float_as_uint(__uint_as_float(c0.z) - __uint_as_float(c0.z & 0xffff0000u));
            uint r3 = __float_as_uint(__uint_as_float(c0.w) - __uint_as_float(c0.w & 0xffff0000u));
            uint r4 = __float_as_uint(__uint_as_float(c1.x) - __uint_as_float(c1.x & 0xffff0000u));
            uint r5 = __float_as_uint(__uint_as_float(c1.y) - __uint_as_float(c1.y & 0xffff0000u));
            uint r6 = __float_as_uint(__uint_as_float(c1.z) - __uint_as_float(c1.z & 0xffff0000u));
            uint r7 = __float_as_uint(__uint_as_float(c1.w) - __uint_as_float(c1.w & 0xffff0000u));
            L.u[0] = __builtin_amdgcn_perm(r1, r0, 0x07060302u);
            L.u[1] = __builtin_amdgcn_perm(r3, r2, 0x07060302u);
            L.u[2] = __builtin_amdgcn_perm(r5, r4, 0x07060302u);
            L.u[3] = __builtin_amdgcn_perm(r7, r6, 0x07060302u);
            ah[i] = H.v; al[i] = L.v;
        }
        #pragma unroll
        for (int i = 0; i < 4; ++i)
            #pragma unroll
            for (int j = 0; j < 4; ++j) {
                acc[i][j] = __builtin_amdgcn_mfma_f32_16x16x32_bf16(ah[i], bh[j], acc[i][j], 0, 0, 0);
                acc[i][j] = __builtin_amdgcn_mfma_f32_16x16x32_bf16(ah[i], bl[j], acc[i][j], 0, 0, 0);
                acc[i][j] = __builtin_amdgcn_mfma_f32_16x16x32_bf16(al[i], bh[j], acc[i][j], 0, 0, 0);
            }
    }

    // epilogue 1: h1b bf16 write (C/D layout col=lane&15, row=quad*4+reg)
    #pragma unroll
    for (int i = 0; i < 4; ++i) {
        int rb = bm + wm + i * 16 + quad * 4;
        #pragma unroll
        for (int j = 0; j < 4; ++j) {
            int col = bn + wn + j * 16 + fm;
            #pragma unroll
            for (int r = 0; r < 4; ++r) {
                int row = rb + r;
                if (row < M) C[(size_t)row * 256 + col] = (ushort)bf16_rne_bits(acc[i][j][r]);
            }
        }
    }

    // epilogue 2: fused scores1. This wave's cols = heads head0, head0+1.
    const int head0 = (bn + wn) >> 5;
    const float asA0 = as1[head0 * 32 + fm],      asA1 = as1[head0 * 32 + 16 + fm];
    const float asB0 = as1[head0 * 32 + 32 + fm], asB1 = as1[head0 * 32 + 48 + fm];
    const float adA0 = ad1[head0 * 32 + fm],      adA1 = ad1[head0 * 32 + 16 + fm];
    const float adB0 = ad1[head0 * 32 + 32 + fm], adB1 = ad1[head0 * 32 + 48 + fm];
    #pragma unroll
    for (int i = 0; i < 4; ++i) {
        #pragma unroll
        for (int r = 0; r < 4; ++r) {
            int row = bm + wm + i * 16 + quad * 4 + r;
            float s1A = acc[i][0][r] * asA0 + acc[i][1][r] * asA1;
            float s1B = acc[i][2][r] * asB0 + acc[i][3][r] * asB1;
            float s2A = acc[i][0][r] * adA0 + acc[i][1][r] * adA1;
            float s2B = acc[i][2][r] * adB0 + acc[i][3][r] * adB1;
            #pragma unroll
            for (int off = 1; off < 16; off <<= 1) {   // reduce across fm (stays in quad group)
                s1A += __shfl_xor(s1A, off);
                s1B += __shfl_xor(s1B, off);
                s2A += __shfl_xor(s2A, off);
                s2B += __shfl_xor(s2B, off);
            }
            if (fm == 0 && row < M) {
                ssrc[(size_t)row * 8 + head0]     = s1A;
                ssrc[(size_t)row * 8 + head0 + 1] = s1B;
                sdst[(size_t)row * 8 + head0]     = s2A;
                sdst[(size_t)row * 8 + head0 + 1] = s2B;
            }
        }
    }
}

// ------------------------------------------------ MFMA GEMM2: h2b[M,32] = out1b @ W2 (2-term) + fused scores2
__global__ void __launch_bounds__(256) gemm2_mfma_kernel(const ushort* __restrict__ A,
        const ushort* __restrict__ bh_g, const ushort* __restrict__ bl_g,
        const float* __restrict__ as2, const float* __restrict__ ad2,
        ushort* __restrict__ C, float* __restrict__ ssrc, float* __restrict__ sdst, int M) {
    __shared__ ushort As[128 * 32];   // 8 KB, phys chunk = row*4 + (q ^ ((row>>1)&3))
    const int tid = threadIdx.x, lane = tid & 63, wave = tid >> 6;
    const int bm = blockIdx.x * 128;
    const int fm = lane & 15, quad = lane >> 4;
    const int wrow = wave * 32;

    const ushort* agp[2]; const ushort* alp[2];
    #pragma unroll
    for (int s = 0; s < 2; ++s) {
        int t = wave * 2 + s;
        int p = t * 64 + lane;           // chunk 0..511
        int row = p >> 2, qs = p & 3;
        int q = qs ^ ((row >> 1) & 3);
        int gr = bm + row; if (gr > M - 1) gr = M - 1;
        agp[s] = A + (size_t)gr * 256 + q * 8;
        alp[s] = &As[t * 512];
    }

    f32x4 acc[2][2] = {};
    for (int kk = 0; kk < 8; ++kk) {
        GLOBAL_LOAD_LDS16(agp[0], alp[0]);
        GLOBAL_LOAD_LDS16(agp[1], alp[1]);
        agp[0] += 32; agp[1] += 32;
        __syncthreads();
        bf16x8 a[2], bh[2], bl[2];
        #pragma unroll
        for (int i = 0; i < 2; ++i) {
            int row = wrow + i * 16 + fm;
            int q = quad ^ ((row >> 1) & 3);
            a[i] = *(const bf16x8*)&As[row * 32 + q * 8];
        }
        #pragma unroll
        for (int j = 0; j < 2; ++j) {
            size_t off = (size_t)(j * 16 + fm) * 256 + kk * 32 + quad * 8;
            bh[j] = *(const bf16x8*)(bh_g + off);
            bl[j] = *(const bf16x8*)(bl_g + off);
        }
        #pragma unroll
        for (int i = 0; i < 2; ++i)
            #pragma unroll
            for (int j = 0; j < 2; ++j) {
                acc[i][j] = __builtin_amdgcn_mfma_f32_16x16x32_bf16(a[i], bh[j], acc[i][j], 0, 0, 0);
                acc[i][j] = __builtin_amdgcn_mfma_f32_16x16x32_bf16(a[i], bl[j], acc[i][j], 0, 0, 0);
            }
        __syncthreads();
    }

    float a0 = as2[fm], a1 = as2[16 + fm];
    float d0 = ad2[fm], d1 = ad2[16 + fm];
    #pragma unroll
    for (int i = 0; i < 2; ++i) {
        #pragma unroll
        for (int r = 0; r < 4; ++r) {
            int rg = bm + wrow + i * 16 + quad * 4 + r;
            float v0 = acc[i][0][r], v1 = acc[i][1][r];
            float s1 = v0 * a0 + v1 * a1;
            float s2 = v0 * d0 + v1 * d1;
            #pragma unroll
            for (int off = 1; off < 16; off <<= 1) {
                s1 += __shfl_xor(s1, off);
                s2 += __shfl_xor(s2, off);
            }
            if (rg < M) {
                C[(size_t)rg * 32 + fm]      = (ushort)bf16_rne_bits(v0);
                C[(size_t)rg * 32 + 16 + fm] = (ushort)bf16_rne_bits(v1);
                if (fm == 0) { ssrc[rg] = s1; sdst[rg] = s2; }
            }
        }
    }
}

// ---------------------------------------------------------------- CSR build
__global__ void count_deg(const int* __restrict__ ei, int* __restrict__ deg) {
    int e = blockIdx.x * blockDim.x + threadIdx.x;
    if (e >= E2) return;
    int dst = (e < N_EDGES) ? ei[N_EDGES + e] : (e - N_EDGES);
    atomicAdd(&deg[dst], 1);
}

#define SCAN_B 256
#define SCAN_NB ((N_NODES + SCAN_B - 1) / SCAN_B)   // 196

__global__ void scan1_kernel(const int* __restrict__ deg, int* __restrict__ rowstart,
                             int* __restrict__ blocksum) {
    __shared__ int sm[SCAN_B];
    int t = threadIdx.x, i = blockIdx.x * SCAN_B + t;
    int v = (i < N_NODES) ? deg[i] : 0;
    sm[t] = v; __syncthreads();
    int x = v;
    for (int off = 1; off < SCAN_B; off <<= 1) {
        int y = (t >= off) ? sm[t - off] : 0; __syncthreads();
        x += y; sm[t] = x; __syncthreads();
    }
    if (i <= N_NODES) rowstart[i] = x - v;
    if (t == SCAN_B - 1) blocksum[blockIdx.x] = x;
}

__global__ void scan2_kernel(const int* __restrict__ blocksum, int* __restrict__ blockoff) {
    __shared__ int sm[256];
    int t = threadIdx.x;
    int v = (t < SCAN_NB) ? blocksum[t] : 0;
    sm[t] = v; __syncthreads();
    int x = v;
    for (int off = 1; off < 256; off <<= 1) {
        int y = (t >= off) ? sm[t - off] : 0; __syncthreads();
        x += y; sm[t] = x; __syncthreads();
    }
    if (t < SCAN_NB) blockoff[t] = x - v;
}

__global__ void fill_csr(const int* __restrict__ ei, const int* __restrict__ rowstart,
                         const int* __restrict__ blockoff,
                         int* __restrict__ cursor, int* __restrict__ csr_src) {
    int e = blockIdx.x * blockDim.x + threadIdx.x;
    if (e >= E2) return;
    int src, dst;
    if (e < N_EDGES) { src = ei[e]; dst = ei[N_EDGES + e]; }
    else             { src = e - N_EDGES; dst = src; }
    int p = atomicAdd(&cursor[dst], 1);
    csr_src[rowstart[dst] + blockoff[dst >> 8] + p] = src;
}

// ---------------------------------------------------------------- layer-1 aggregation
// one wave per node; SINGLE PASS (no-max softmax): acc = sum w*h, sw = sum w.
// weight computed once per edge per head (lane hl of head group hg), batched
// shuffle-broadcast then 8 loads in flight.
__global__ void __launch_bounds__(256) agg1_wave_kernel(const ushort* __restrict__ h,
        const float* __restrict__ ssrc, const float* __restrict__ sdst,
        const int* __restrict__ rowstart, const int* __restrict__ blockoff,
        const int* __restrict__ csr_src,
        const float* __restrict__ bias, ushort* __restrict__ out) {
    const int wid = (blockIdx.x * blockDim.x + threadIdx.x) >> 6;   // node id
    if (wid >= N_NODES) return;
    const int lane = threadIdx.x & 63;
    const int hg = lane >> 3;
    const int hl = lane & 7;
    const int n = wid;
    const int beg = rowstart[n] + blockoff[n >> 8];
    const int end = rowstart[n + 1] + blockoff[(n + 1) >> 8];
    const float sdst_n = sdst[(size_t)n * HEADS + hg];

    float4 acc = make_float4(0.f, 0.f, 0.f, 0.f);
    float sw = 0.f;
    const ushort* hc = h + lane * 4;
    const int base = hg << 3;
    for (int e = beg; e < end; e += 8) {
        int ee = e + hl;
        int eidx = ee < end ? ee : end - 1;
        int src_h = csr_src[eidx];
        float sc = ssrc[(size_t)src_h * HEADS + hg] + sdst_n;
        sc = sc > 0.f ? sc : NEG_SLOPE * sc;
        float w_h = (ee < end) ? __expf(sc) : 0.f;
        float wj[8]; int sj[8];
        #pragma unroll
        for (int j = 0; j < 8; ++j) {
            wj[j] = __shfl(w_h, base + j);
            sj[j] = __shfl(src_h, base + j);
        }
        ushort4 v[8];
        #pragma unroll
        for (int j = 0; j < 8; ++j) v[j] = *(const ushort4*)(hc + (size_t)sj[j] * HC);
        #pragma unroll
        for (int j = 0; j < 8; ++j) {
            acc.x += wj[j] * bf2f(v[j].x);
            acc.y += wj[j] * bf2f(v[j].y);
            acc.z += wj[j] * bf2f(v[j].z);
            acc.w += wj[j] * bf2f(v[j].w);
            sw += wj[j];
        }
    }
    float inv = 1.f / (sw + 1e-16f);
    float4 bv = *(const float4*)(bias + lane * 4);
    float4 o;
    o.x = acc.x * inv + bv.x; o.y = acc.y * inv + bv.y;
    o.z = acc.z * inv + bv.z; o.w = acc.w * inv + bv.w;
    o.x = o.x > 0.f ? o.x : expm1f(o.x);
    o.y = o.y > 0.f ? o.y : expm1f(o.y);
    o.z = o.z > 0.f ? o.z : expm1f(o.z);
    o.w = o.w > 0.f ? o.w : expm1f(o.w);
    ushort4 ob;
    ob.x = (ushort)bf16_rne_bits(o.x);
    ob.y = (ushort)bf16_rne_bits(o.y);
    ob.z = (ushort)bf16_rne_bits(o.z);
    ob.w = (ushort)bf16_rne_bits(o.w);
    *(ushort4*)(out + (size_t)n * HC + lane * 4) = ob;
}

// ---------------------------------------------------------------- layer-2 aggregation (single pass)
__global__ void __launch_bounds__(64) agg2_kernel(const ushort* __restrict__ h2,
        const float* __restrict__ ssrc, const float* __restrict__ sdst,
        const int* __restrict__ rowstart, const int* __restrict__ blockoff,
        const int* __restrict__ csr_src,
        const float* __restrict__ bias, float* __restrict__ out) {
    const int n = blockIdx.x;
    const int beg = rowstart[n] + blockoff[n >> 8];
    const int end = rowstart[n + 1] + blockoff[(n + 1) >> 8];
    const int t = threadIdx.x;
    const float sdst_n = sdst[n];

    const int slot = t >> 4, cp = t & 15;   // channels 2cp, 2cp+1
    float a0 = 0.f, a1 = 0.f, sw = 0.f;
    for (int e = beg + slot; e < end; e += 4) {
        int src = csr_src[e];
        float sc = ssrc[src] + sdst_n;
        sc = sc > 0.f ? sc : NEG_SLOPE * sc;
        float w = __expf(sc);
        uint v = *(const uint*)(h2 + (size_t)src * NCLASS + cp * 2);
        a0 += w * __uint_as_float(v << 16);
        a1 += w * __uint_as_float(v & 0xffff0000u);
        sw += w;
    }
    a0 += __shfl_down(a0, 32); a1 += __shfl_down(a1, 32); sw += __shfl_down(sw, 32);
    a0 += __shfl_down(a0, 16); a1 += __shfl_down(a1, 16); sw += __shfl_down(sw, 16);
    if (t < 16) {
        float inv = 1.f / (sw + 1e-16f);
        float2 o;
        o.x = a0 * inv + bias[cp * 2]     + 1e-6f;
        o.y = a1 * inv + bias[cp * 2 + 1] + 1e-6f;
        *(float2*)(out + (size_t)n * NCLASS + cp * 2) = o;
    }
}

// ---------------------------------------------------------------- launcher
extern "C" void kernel_launch(void* const* d_in, const int* in_sizes, int n_in,
                              void* d_out, int out_size, void* d_ws, size_t ws_size,
                              hipStream_t stream) {
    const float* x        = (const float*)d_in[0];
    const int*   ei       = (const int*)  d_in[1];
    const float* W1       = (const float*)d_in[2];
    const float* att_src1 = (const float*)d_in[3];
    const float* att_dst1 = (const float*)d_in[4];
    const float* b1       = (const float*)d_in[5];
    const float* W2       = (const float*)d_in[6];
    const float* att_src2 = (const float*)d_in[7];
    const float* att_dst2 = (const float*)d_in[8];
    const float* b2       = (const float*)d_in[9];
    float* out = (float*)d_out;

    // workspace layout
    ushort* w1t_hi = (ushort*)d_ws;                        // 131072
    ushort* w1t_lo = w1t_hi + 256 * 512;                   // 131072
    ushort* w2t_hi = w1t_lo + 256 * 512;                   // 8192
    ushort* w2t_lo = w2t_hi + 32 * 256;                    // 8192
    ushort* h1b    = w2t_lo + 32 * 256;                    // N*HC bf16
    ushort* h2b    = h1b + (size_t)N_NODES * HC;           // N*NCLASS bf16
    ushort* out1b  = h2b + (size_t)N_NODES * NCLASS;       // N*HC bf16
    float* ssrc1 = (float*)(out1b + (size_t)N_NODES * HC); // N*HEADS
    float* sdst1 = ssrc1 + (size_t)N_NODES * HEADS;        // N*HEADS
    float* ssrc2 = sdst1 + (size_t)N_NODES * HEADS;        // N
    float* sdst2 = ssrc2 + N_NODES;                        // N
    int* rowstart = (int*)(sdst2 + N_NODES);               // N+1
    int* deg      = rowstart + N_NODES + 1;                // N   (deg+cursor zeroed together)
    int* cursor   = deg + N_NODES;                         // N
    int* csr_src  = cursor + N_NODES;                      // E2
    int* blocksum = csr_src + E2;                          // SCAN_NB
    int* blockoff = blocksum + SCAN_NB;                    // SCAN_NB

    // CSR build (rowstart kept block-local; consumers add blockoff[i>>8])
    hipMemsetAsync(deg, 0, 2 * N_NODES * sizeof(int), stream);   // deg + cursor
    int eb = (E2 + 255) / 256;
    count_deg<<<eb, 256, 0, stream>>>(ei, deg);
    scan1_kernel<<<SCAN_NB, SCAN_B, 0, stream>>>(deg, rowstart, blocksum);
    scan2_kernel<<<1, 256, 0, stream>>>(blocksum, blockoff);
    fill_csr<<<eb, 256, 0, stream>>>(ei, rowstart, blockoff, cursor, csr_src);

    // weight splits
    split_w1t_kernel<<<(256 * 512) / 256, 256, 0, stream>>>(W1, w1t_hi, w1t_lo);
    split_w2t_kernel<<<(32 * 256) / 256, 256, 0, stream>>>(W2, w2t_hi, w2t_lo);

    // layer 1: MFMA GEMM (no-LDS direct) -> bf16 h1 + fused scores1
    {
        dim3 grid((N_NODES + 127) / 128, HC / 128);
        gemm1_mfma_kernel<<<grid, 256, 0, stream>>>((const uint*)x, w1t_hi, w1t_lo,
                att_src1, att_dst1, h1b, ssrc1, sdst1, N_NODES);
    }
    agg1_wave_kernel<<<(N_NODES + 3) / 4, 256, 0, stream>>>(h1b, ssrc1, sdst1, rowstart, blockoff, csr_src, b1, out1b);

    // layer 2: MFMA GEMM -> bf16 h2 + fused scores2
    gemm2_mfma_kernel<<<(N_NODES + 127) / 128, 256, 0, stream>>>(out1b, w2t_hi, w2t_lo,
            att_src2, att_dst2, h2b, ssrc2, sdst2, N_NODES);
    agg2_kernel<<<N_NODES, 64, 0, stream>>>(h2b, ssrc2, sdst2, rowstart, blockoff, csr_src, b2, out);
}

// Round 11
// 415.554 us; speedup vs baseline: 1.1437x; 1.1437x over previous
//
#include <hip/hip_runtime.h>
#include <math.h>

#define N_NODES 50000
#define N_EDGES 800000
#define E2 (N_EDGES + N_NODES)   // with self loops
#define F_IN 512
#define HEADS 8
#define HID 32
#define HC 256                    // HEADS*HID
#define NCLASS 32
#define NEG_SLOPE 0.2f

typedef unsigned int uint;
typedef unsigned short ushort;
typedef __attribute__((ext_vector_type(8))) short bf16x8;   // 8 bf16 (4 VGPRs)
typedef __attribute__((ext_vector_type(4))) float f32x4;

#define GLOBAL_LOAD_LDS16(g, l) \
    __builtin_amdgcn_global_load_lds((const __attribute__((address_space(1))) void*)(g), \
                                     (__attribute__((address_space(3))) void*)(l), 16, 0, 0)

__device__ inline uint bf16_rne_bits(float f) {
    uint u = __float_as_uint(f);
    return (u + 0x7fffu + ((u >> 16) & 1u)) >> 16;
}
__device__ inline float bf2f(ushort u) { return __uint_as_float(((uint)u) << 16); }

// ------------------------------------------------ W1 [512][256] -> W1^T hi/lo bf16 [256][512]
__global__ void split_w1t_kernel(const float* __restrict__ W1,
                                 ushort* __restrict__ hi, ushort* __restrict__ lo) {
    int t = blockIdx.x * 256 + threadIdx.x;      // t = n*512 + k, t < 131072
    int n = t >> 9, k = t & 511;
    float f = W1[k * 256 + n];
    uint h = bf16_rne_bits(f);
    float r = f - __uint_as_float(h << 16);
    hi[t] = (ushort)h;
    lo[t] = (ushort)bf16_rne_bits(r);
}

// ------------------------------------------------ W2 [256][32] -> W2^T hi/lo bf16 [32][256]
__global__ void split_w2t_kernel(const float* __restrict__ W2,
                                 ushort* __restrict__ hi, ushort* __restrict__ lo) {
    int t = blockIdx.x * 256 + threadIdx.x;      // t = n*256 + k, t < 8192
    int n = t >> 8, k = t & 255;
    float f = W2[k * 32 + n];
    uint h = bf16_rne_bits(f);
    float r = f - __uint_as_float(h << 16);
    hi[t] = (ushort)h;
    lo[t] = (ushort)bf16_rne_bits(r);
}

// ------------------------------------------------ MFMA GEMM1: h1b[M,256] = x @ W1 (split bf16, 3-term)
// R7's proven two-barrier LDS-staged K-loop, but 64x128 tile: grid 1564 blocks
// (6.1 blocks/CU vs 3.05) so cross-block wave overlap hides the barrier drains.
// LDS 24 KB. + fused scores1 from fp32 acc.
__global__ void __launch_bounds__(256) gemm1_mfma_kernel(const uint* __restrict__ xp,
        const ushort* __restrict__ bhi, const ushort* __restrict__ blo,
        const float* __restrict__ as1, const float* __restrict__ ad1,
        ushort* __restrict__ C, float* __restrict__ ssrc, float* __restrict__ sdst, int M) {
    __shared__ uint   As[64 * 32];    // 8 KB fp32 bits, phys chunk = row*8 + (c ^ (row&7))
    __shared__ ushort Bh[128 * 32];   // 8 KB,  phys chunk = row*4 + (q ^ ((row>>1)&3))
    __shared__ ushort Bl[128 * 32];   // 8 KB
    const int tid = threadIdx.x, lane = tid & 63, wave = tid >> 6;
    const int bm = blockIdx.x * 64, bn = blockIdx.y * 128;
    const int fm = lane & 15, quad = lane >> 4;
    const int wm = (wave >> 1) * 32, wn = (wave & 1) * 64;

    // A staging: 512 chunks of 16B (64 rows x 8 chunks), 2 per thread
    const uint* agp[2]; const uint* alp[2];
    #pragma unroll
    for (int s = 0; s < 2; ++s) {
        int t = wave * 2 + s;
        int p = t * 64 + lane;           // physical chunk 0..511
        int row = p >> 3, cs = p & 7;
        int c = cs ^ (row & 7);          // global k-chunk (4 u32 each)
        int grow = bm + row; if (grow > M - 1) grow = M - 1;
        agp[s] = xp + ((size_t)grow * 512 + c * 4);
        alp[s] = &As[t * 256];           // wave-uniform LDS base; HW adds lane*16B
    }
    // B staging: 512 chunks each for hi/lo (128 rows x 4 chunks), 2+2 per thread
    const ushort* bhgp[2]; const ushort* blgp[2]; const ushort* bhlp[2]; const ushort* bllp[2];
    #pragma unroll
    for (int s = 0; s < 2; ++s) {
        int t = wave * 2 + s;
        int p = t * 64 + lane;           // physical chunk 0..511
        int row = p >> 2, qs = p & 3;
        int q = qs ^ ((row >> 1) & 3);   // global k-chunk (8 bf16 each)
        size_t go = (size_t)(bn + row) * 512 + q * 8;
        bhgp[s] = bhi + go; blgp[s] = blo + go;
        bhlp[s] = &Bh[t * 512]; bllp[s] = &Bl[t * 512];
    }

    f32x4 acc[2][4] = {};

    for (int kk = 0; kk < 16; ++kk) {
        #pragma unroll
        for (int s = 0; s < 2; ++s) {
            GLOBAL_LOAD_LDS16(agp[s], alp[s]);
            GLOBAL_LOAD_LDS16(bhgp[s], bhlp[s]);
            GLOBAL_LOAD_LDS16(blgp[s], bllp[s]);
        }
        #pragma unroll
        for (int s = 0; s < 2; ++s) { agp[s] += 32; bhgp[s] += 32; blgp[s] += 32; }
        __syncthreads();   // drains vmcnt: staged data visible

        bf16x8 ah[2], al[2], bh[4], bl[4];
        #pragma unroll
        for (int i = 0; i < 2; ++i) {
            int row = wm + i * 16 + fm;
            int sw = row & 7;
            uint4 c0 = *(const uint4*)&As[row * 32 + (((2 * quad)     ^ sw) * 4)];
            uint4 c1 = *(const uint4*)&As[row * 32 + (((2 * quad + 1) ^ sw) * 4)];
            union { uint u[4]; bf16x8 v; } H, L;
            H.u[0] = __builtin_amdgcn_perm(c0.y, c0.x, 0x07060302u);
            H.u[1] = __builtin_amdgcn_perm(c0.w, c0.z, 0x07060302u);
            H.u[2] = __builtin_amdgcn_perm(c1.y, c1.x, 0x07060302u);
            H.u[3] = __builtin_amdgcn_perm(c1.w, c1.z, 0x07060302u);
            uint r0 = __float_as_uint(__uint_as_float(c0.x) - __uint_as_float(c0.x & 0xffff0000u));
            uint r1 = __float_as_uint(__uint_as_float(c0.y) - __uint_as_float(c0.y & 0xffff0000u));
            uint r2 = __float_as_uint(__uint_as_float(c0.z) - __uint_as_float(c0.z & 0xffff0000u));
            uint r3 = __float_as_uint(__uint_as_float(c0.w) - __uint_as_float(c0.w & 0xffff0000u));
            uint r4 = __float_as_uint(__uint_as_float(c1.x) - __uint_as_float(c1.x & 0xffff0000u));
            uint r5 = __float_as_uint(__uint_as_float(c1.y) - __uint_as_float(c1.y & 0xffff0000u));
            uint r6 = __float_as_uint(__uint_as_float(c1.z) - __uint_as_float(c1.z & 0xffff0000u));
            uint r7 = __float_as_uint(__uint_as_float(c1.w) - __uint_as_float(c1.w & 0xffff0000u));
            L.u[0] = __builtin_amdgcn_perm(r1, r0, 0x07060302u);
            L.u[1] = __builtin_amdgcn_perm(r3, r2, 0x07060302u);
            L.u[2] = __builtin_amdgcn_perm(r5, r4, 0x07060302u);
            L.u[3] = __builtin_amdgcn_perm(r7, r6, 0x07060302u);
            ah[i] = H.v; al[i] = L.v;
        }
        #pragma unroll
        for (int j = 0; j < 4; ++j) {
            int row = wn + j * 16 + fm;
            int qs = quad ^ ((row >> 1) & 3);
            bh[j] = *(const bf16x8*)&Bh[row * 32 + qs * 8];
            bl[j] = *(const bf16x8*)&Bl[row * 32 + qs * 8];
        }
        #pragma unroll
        for (int i = 0; i < 2; ++i)
            #pragma unroll
            for (int j = 0; j < 4; ++j) {
                acc[i][j] = __builtin_amdgcn_mfma_f32_16x16x32_bf16(ah[i], bh[j], acc[i][j], 0, 0, 0);
                acc[i][j] = __builtin_amdgcn_mfma_f32_16x16x32_bf16(ah[i], bl[j], acc[i][j], 0, 0, 0);
                acc[i][j] = __builtin_amdgcn_mfma_f32_16x16x32_bf16(al[i], bh[j], acc[i][j], 0, 0, 0);
            }
        __syncthreads();
    }

    // epilogue 1: h1b bf16 write (C/D layout col=lane&15, row=quad*4+reg)
    #pragma unroll
    for (int i = 0; i < 2; ++i) {
        int rb = bm + wm + i * 16 + quad * 4;
        #pragma unroll
        for (int j = 0; j < 4; ++j) {
            int col = bn + wn + j * 16 + fm;
            #pragma unroll
            for (int r = 0; r < 4; ++r) {
                int row = rb + r;
                if (row < M) C[(size_t)row * 256 + col] = (ushort)bf16_rne_bits(acc[i][j][r]);
            }
        }
    }

    // epilogue 2: fused scores1. This wave's cols = heads head0, head0+1.
    const int head0 = (bn + wn) >> 5;
    const float asA0 = as1[head0 * 32 + fm],      asA1 = as1[head0 * 32 + 16 + fm];
    const float asB0 = as1[head0 * 32 + 32 + fm], asB1 = as1[head0 * 32 + 48 + fm];
    const float adA0 = ad1[head0 * 32 + fm],      adA1 = ad1[head0 * 32 + 16 + fm];
    const float adB0 = ad1[head0 * 32 + 32 + fm], adB1 = ad1[head0 * 32 + 48 + fm];
    #pragma unroll
    for (int i = 0; i < 2; ++i) {
        #pragma unroll
        for (int r = 0; r < 4; ++r) {
            int row = bm + wm + i * 16 + quad * 4 + r;
            float s1A = acc[i][0][r] * asA0 + acc[i][1][r] * asA1;
            float s1B = acc[i][2][r] * asB0 + acc[i][3][r] * asB1;
            float s2A = acc[i][0][r] * adA0 + acc[i][1][r] * adA1;
            float s2B = acc[i][2][r] * adB0 + acc[i][3][r] * adB1;
            #pragma unroll
            for (int off = 1; off < 16; off <<= 1) {   // reduce across fm (stays in quad group)
                s1A += __shfl_xor(s1A, off);
                s1B += __shfl_xor(s1B, off);
                s2A += __shfl_xor(s2A, off);
                s2B += __shfl_xor(s2B, off);
            }
            if (fm == 0 && row < M) {
                ssrc[(size_t)row * 8 + head0]     = s1A;
                ssrc[(size_t)row * 8 + head0 + 1] = s1B;
                sdst[(size_t)row * 8 + head0]     = s2A;
                sdst[(size_t)row * 8 + head0 + 1] = s2B;
            }
        }
    }
}

// ------------------------------------------------ MFMA GEMM2: h2b[M,32] = out1b @ W2 (2-term) + fused scores2
__global__ void __launch_bounds__(256) gemm2_mfma_kernel(const ushort* __restrict__ A,
        const ushort* __restrict__ bh_g, const ushort* __restrict__ bl_g,
        const float* __restrict__ as2, const float* __restrict__ ad2,
        ushort* __restrict__ C, float* __restrict__ ssrc, float* __restrict__ sdst, int M) {
    __shared__ ushort As[128 * 32];   // 8 KB, phys chunk = row*4 + (q ^ ((row>>1)&3))
    const int tid = threadIdx.x, lane = tid & 63, wave = tid >> 6;
    const int bm = blockIdx.x * 128;
    const int fm = lane & 15, quad = lane >> 4;
    const int wrow = wave * 32;

    const ushort* agp[2]; const ushort* alp[2];
    #pragma unroll
    for (int s = 0; s < 2; ++s) {
        int t = wave * 2 + s;
        int p = t * 64 + lane;           // chunk 0..511
        int row = p >> 2, qs = p & 3;
        int q = qs ^ ((row >> 1) & 3);
        int gr = bm + row; if (gr > M - 1) gr = M - 1;
        agp[s] = A + (size_t)gr * 256 + q * 8;
        alp[s] = &As[t * 512];
    }

    f32x4 acc[2][2] = {};
    for (int kk = 0; kk < 8; ++kk) {
        GLOBAL_LOAD_LDS16(agp[0], alp[0]);
        GLOBAL_LOAD_LDS16(agp[1], alp[1]);
        agp[0] += 32; agp[1] += 32;
        __syncthreads();
        bf16x8 a[2], bh[2], bl[2];
        #pragma unroll
        for (int i = 0; i < 2; ++i) {
            int row = wrow + i * 16 + fm;
            int q = quad ^ ((row >> 1) & 3);
            a[i] = *(const bf16x8*)&As[row * 32 + q * 8];
        }
        #pragma unroll
        for (int j = 0; j < 2; ++j) {
            size_t off = (size_t)(j * 16 + fm) * 256 + kk * 32 + quad * 8;
            bh[j] = *(const bf16x8*)(bh_g + off);
            bl[j] = *(const bf16x8*)(bl_g + off);
        }
        #pragma unroll
        for (int i = 0; i < 2; ++i)
            #pragma unroll
            for (int j = 0; j < 2; ++j) {
                acc[i][j] = __builtin_amdgcn_mfma_f32_16x16x32_bf16(a[i], bh[j], acc[i][j], 0, 0, 0);
                acc[i][j] = __builtin_amdgcn_mfma_f32_16x16x32_bf16(a[i], bl[j], acc[i][j], 0, 0, 0);
            }
        __syncthreads();
    }

    float a0 = as2[fm], a1 = as2[16 + fm];
    float d0 = ad2[fm], d1 = ad2[16 + fm];
    #pragma unroll
    for (int i = 0; i < 2; ++i) {
        #pragma unroll
        for (int r = 0; r < 4; ++r) {
            int rg = bm + wrow + i * 16 + quad * 4 + r;
            float v0 = acc[i][0][r], v1 = acc[i][1][r];
            float s1 = v0 * a0 + v1 * a1;
            float s2 = v0 * d0 + v1 * d1;
            #pragma unroll
            for (int off = 1; off < 16; off <<= 1) {
                s1 += __shfl_xor(s1, off);
                s2 += __shfl_xor(s2, off);
            }
            if (rg < M) {
                C[(size_t)rg * 32 + fm]      = (ushort)bf16_rne_bits(v0);
                C[(size_t)rg * 32 + 16 + fm] = (ushort)bf16_rne_bits(v1);
                if (fm == 0) { ssrc[rg] = s1; sdst[rg] = s2; }
            }
        }
    }
}

// ---------------------------------------------------------------- CSR build
__global__ void count_deg(const int* __restrict__ ei, int* __restrict__ deg) {
    int e = blockIdx.x * blockDim.x + threadIdx.x;
    if (e >= E2) return;
    int dst = (e < N_EDGES) ? ei[N_EDGES + e] : (e - N_EDGES);
    atomicAdd(&deg[dst], 1);
}

#define SCAN_B 256
#define SCAN_NB ((N_NODES + SCAN_B - 1) / SCAN_B)   // 196

__global__ void scan1_kernel(const int* __restrict__ deg, int* __restrict__ rowstart,
                             int* __restrict__ blocksum) {
    __shared__ int sm[SCAN_B];
    int t = threadIdx.x, i = blockIdx.x * SCAN_B + t;
    int v = (i < N_NODES) ? deg[i] : 0;
    sm[t] = v; __syncthreads();
    int x = v;
    for (int off = 1; off < SCAN_B; off <<= 1) {
        int y = (t >= off) ? sm[t - off] : 0; __syncthreads();
        x += y; sm[t] = x; __syncthreads();
    }
    if (i <= N_NODES) rowstart[i] = x - v;
    if (t == SCAN_B - 1) blocksum[blockIdx.x] = x;
}

__global__ void scan2_kernel(const int* __restrict__ blocksum, int* __restrict__ blockoff) {
    __shared__ int sm[256];
    int t = threadIdx.x;
    int v = (t < SCAN_NB) ? blocksum[t] : 0;
    sm[t] = v; __syncthreads();
    int x = v;
    for (int off = 1; off < 256; off <<= 1) {
        int y = (t >= off) ? sm[t - off] : 0; __syncthreads();
        x += y; sm[t] = x; __syncthreads();
    }
    if (t < SCAN_NB) blockoff[t] = x - v;
}

__global__ void fill_csr(const int* __restrict__ ei, const int* __restrict__ rowstart,
                         const int* __restrict__ blockoff,
                         int* __restrict__ cursor, int* __restrict__ csr_src) {
    int e = blockIdx.x * blockDim.x + threadIdx.x;
    if (e >= E2) return;
    int src, dst;
    if (e < N_EDGES) { src = ei[e]; dst = ei[N_EDGES + e]; }
    else             { src = e - N_EDGES; dst = src; }
    int p = atomicAdd(&cursor[dst], 1);
    csr_src[rowstart[dst] + blockoff[dst >> 8] + p] = src;
}

// ---------------------------------------------------------------- layer-1 aggregation
// one wave per node; SINGLE PASS (no-max softmax): acc = sum w*h, sw = sum w.
// weight computed once per edge per head (lane hl of head group hg), batched
// shuffle-broadcast then 8 loads in flight.
__global__ void __launch_bounds__(256) agg1_wave_kernel(const ushort* __restrict__ h,
        const float* __restrict__ ssrc, const float* __restrict__ sdst,
        const int* __restrict__ rowstart, const int* __restrict__ blockoff,
        const int* __restrict__ csr_src,
        const float* __restrict__ bias, ushort* __restrict__ out) {
    const int wid = (blockIdx.x * blockDim.x + threadIdx.x) >> 6;   // node id
    if (wid >= N_NODES) return;
    const int lane = threadIdx.x & 63;
    const int hg = lane >> 3;
    const int hl = lane & 7;
    const int n = wid;
    const int beg = rowstart[n] + blockoff[n >> 8];
    const int end = rowstart[n + 1] + blockoff[(n + 1) >> 8];
    const float sdst_n = sdst[(size_t)n * HEADS + hg];

    float4 acc = make_float4(0.f, 0.f, 0.f, 0.f);
    float sw = 0.f;
    const ushort* hc = h + lane * 4;
    const int base = hg << 3;
    for (int e = beg; e < end; e += 8) {
        int ee = e + hl;
        int eidx = ee < end ? ee : end - 1;
        int src_h = csr_src[eidx];
        float sc = ssrc[(size_t)src_h * HEADS + hg] + sdst_n;
        sc = sc > 0.f ? sc : NEG_SLOPE * sc;
        float w_h = (ee < end) ? __expf(sc) : 0.f;
        float wj[8]; int sj[8];
        #pragma unroll
        for (int j = 0; j < 8; ++j) {
            wj[j] = __shfl(w_h, base + j);
            sj[j] = __shfl(src_h, base + j);
        }
        ushort4 v[8];
        #pragma unroll
        for (int j = 0; j < 8; ++j) v[j] = *(const ushort4*)(hc + (size_t)sj[j] * HC);
        #pragma unroll
        for (int j = 0; j < 8; ++j) {
            acc.x += wj[j] * bf2f(v[j].x);
            acc.y += wj[j] * bf2f(v[j].y);
            acc.z += wj[j] * bf2f(v[j].z);
            acc.w += wj[j] * bf2f(v[j].w);
            sw += wj[j];
        }
    }
    float inv = 1.f / (sw + 1e-16f);
    float4 bv = *(const float4*)(bias + lane * 4);
    float4 o;
    o.x = acc.x * inv + bv.x; o.y = acc.y * inv + bv.y;
    o.z = acc.z * inv + bv.z; o.w = acc.w * inv + bv.w;
    o.x = o.x > 0.f ? o.x : expm1f(o.x);
    o.y = o.y > 0.f ? o.y : expm1f(o.y);
    o.z = o.z > 0.f ? o.z : expm1f(o.z);
    o.w = o.w > 0.f ? o.w : expm1f(o.w);
    ushort4 ob;
    ob.x = (ushort)bf16_rne_bits(o.x);
    ob.y = (ushort)bf16_rne_bits(o.y);
    ob.z = (ushort)bf16_rne_bits(o.z);
    ob.w = (ushort)bf16_rne_bits(o.w);
    *(ushort4*)(out + (size_t)n * HC + lane * 4) = ob;
}

// ---------------------------------------------------------------- layer-2 aggregation (single pass)
__global__ void __launch_bounds__(64) agg2_kernel(const ushort* __restrict__ h2,
        const float* __restrict__ ssrc, const float* __restrict__ sdst,
        const int* __restrict__ rowstart, const int* __restrict__ blockoff,
        const int* __restrict__ csr_src,
        const float* __restrict__ bias, float* __restrict__ out) {
    const int n = blockIdx.x;
    const int beg = rowstart[n] + blockoff[n >> 8];
    const int end = rowstart[n + 1] + blockoff[(n + 1) >> 8];
    const int t = threadIdx.x;
    const float sdst_n = sdst[n];

    const int slot = t >> 4, cp = t & 15;   // channels 2cp, 2cp+1
    float a0 = 0.f, a1 = 0.f, sw = 0.f;
    for (int e = beg + slot; e < end; e += 4) {
        int src = csr_src[e];
        float sc = ssrc[src] + sdst_n;
        sc = sc > 0.f ? sc : NEG_SLOPE * sc;
        float w = __expf(sc);
        uint v = *(const uint*)(h2 + (size_t)src * NCLASS + cp * 2);
        a0 += w * __uint_as_float(v << 16);
        a1 += w * __uint_as_float(v & 0xffff0000u);
        sw += w;
    }
    a0 += __shfl_down(a0, 32); a1 += __shfl_down(a1, 32); sw += __shfl_down(sw, 32);
    a0 += __shfl_down(a0, 16); a1 += __shfl_down(a1, 16); sw += __shfl_down(sw, 16);
    if (t < 16) {
        float inv = 1.f / (sw + 1e-16f);
        float2 o;
        o.x = a0 * inv + bias[cp * 2]     + 1e-6f;
        o.y = a1 * inv + bias[cp * 2 + 1] + 1e-6f;
        *(float2*)(out + (size_t)n * NCLASS + cp * 2) = o;
    }
}

// ---------------------------------------------------------------- launcher
extern "C" void kernel_launch(void* const* d_in, const int* in_sizes, int n_in,
                              void* d_out, int out_size, void* d_ws, size_t ws_size,
                              hipStream_t stream) {
    const float* x        = (const float*)d_in[0];
    const int*   ei       = (const int*)  d_in[1];
    const float* W1       = (const float*)d_in[2];
    const float* att_src1 = (const float*)d_in[3];
    const float* att_dst1 = (const float*)d_in[4];
    const float* b1       = (const float*)d_in[5];
    const float* W2       = (const float*)d_in[6];
    const float* att_src2 = (const float*)d_in[7];
    const float* att_dst2 = (const float*)d_in[8];
    const float* b2       = (const float*)d_in[9];
    float* out = (float*)d_out;

    // workspace layout
    ushort* w1t_hi = (ushort*)d_ws;                        // 131072
    ushort* w1t_lo = w1t_hi + 256 * 512;                   // 131072
    ushort* w2t_hi = w1t_lo + 256 * 512;                   // 8192
    ushort* w2t_lo = w2t_hi + 32 * 256;                    // 8192
    ushort* h1b    = w2t_lo + 32 * 256;                    // N*HC bf16
    ushort* h2b    = h1b + (size_t)N_NODES * HC;           // N*NCLASS bf16
    ushort* out1b  = h2b + (size_t)N_NODES * NCLASS;       // N*HC bf16
    float* ssrc1 = (float*)(out1b + (size_t)N_NODES * HC); // N*HEADS
    float* sdst1 = ssrc1 + (size_t)N_NODES * HEADS;        // N*HEADS
    float* ssrc2 = sdst1 + (size_t)N_NODES * HEADS;        // N
    float* sdst2 = ssrc2 + N_NODES;                        // N
    int* rowstart = (int*)(sdst2 + N_NODES);               // N+1
    int* deg      = rowstart + N_NODES + 1;                // N   (deg+cursor zeroed together)
    int* cursor   = deg + N_NODES;                         // N
    int* csr_src  = cursor + N_NODES;                      // E2
    int* blocksum = csr_src + E2;                          // SCAN_NB
    int* blockoff = blocksum + SCAN_NB;                    // SCAN_NB

    // CSR build (rowstart kept block-local; consumers add blockoff[i>>8])
    hipMemsetAsync(deg, 0, 2 * N_NODES * sizeof(int), stream);   // deg + cursor
    int eb = (E2 + 255) / 256;
    count_deg<<<eb, 256, 0, stream>>>(ei, deg);
    scan1_kernel<<<SCAN_NB, SCAN_B, 0, stream>>>(deg, rowstart, blocksum);
    scan2_kernel<<<1, 256, 0, stream>>>(blocksum, blockoff);
    fill_csr<<<eb, 256, 0, stream>>>(ei, rowstart, blockoff, cursor, csr_src);

    // weight splits
    split_w1t_kernel<<<(256 * 512) / 256, 256, 0, stream>>>(W1, w1t_hi, w1t_lo);
    split_w2t_kernel<<<(32 * 256) / 256, 256, 0, stream>>>(W2, w2t_hi, w2t_lo);

    // layer 1: MFMA GEMM (64x128 tile) -> bf16 h1 + fused scores1
    {
        dim3 grid((N_NODES + 63) / 64, HC / 128);
        gemm1_mfma_kernel<<<grid, 256, 0, stream>>>((const uint*)x, w1t_hi, w1t_lo,
                att_src1, att_dst1, h1b, ssrc1, sdst1, N_NODES);
    }
    agg1_wave_kernel<<<(N_NODES + 3) / 4, 256, 0, stream>>>(h1b, ssrc1, sdst1, rowstart, blockoff, csr_src, b1, out1b);

    // layer 2: MFMA GEMM -> bf16 h2 + fused scores2
    gemm2_mfma_kernel<<<(N_NODES + 127) / 128, 256, 0, stream>>>(out1b, w2t_hi, w2t_lo,
            att_src2, att_dst2, h2b, ssrc2, sdst2, N_NODES);
    agg2_kernel<<<N_NODES, 64, 0, stream>>>(h2b, ssrc2, sdst2, rowstart, blockoff, csr_src, b2, out);
}